// Round 7
// baseline (550.229 us; speedup 1.0000x reference)
//
#include <hip/hip_runtime.h>
#include <hip/hip_cooperative_groups.h>

namespace cg = cooperative_groups;

// ---------------------------------------------------------------------------
// colorableGNN: 3x GCN(128->128) + FC(128->128) + FC(128->2) + mean-pool + softmax
// R21 = R20 with compile fix (hipDeviceAttributeMultiprocessorCount spelling).
//  COOPERATIVE PERSISTENT MEGA-KERNEL. All 10 phases in one launch with
//  grid.sync() boundaries: removes 9 inter-dispatch gaps AND makes the whole
//  pipeline visible to rocprof as one dispatch (counters finally readable).
//  - LDS union 24.6 KB (bin footprint) -> agg phases keep 3-4 blocks/CU.
//  - GEMM phases: M=64 A-tile in LDS, W fragments read DIRECT from global
//    (32 KB L2-resident; no Ws staging -- avoids R19's traffic doubling).
//  - No VGPR caps (R19 lesson). Phase bodies = proven R18 code, grid-strided.
//  - Grid sized via hipOccupancyMaxActiveBlocksPerMultiprocessor (co-residency
//    guaranteed). If query fails -> fallback multi-dispatch path.
// NOTE: gather kernels need occupancy; never fuse agg into GEMM (R7: 104us).
// ---------------------------------------------------------------------------

#define CH 128
#define BSH 7              // 128 dst nodes per bucket
#define SEG 4096           // raw segment capacity (records) per bucket
#define SEGP 5120          // padded epack segment (4B records) per bucket
#define EPW 2048           // edges per bin task
#define SAF 136            // LDS stride tiles (shorts; 272B = 17*16B)
#define SC8 144            // fp8 epilogue stride (bytes)
#define SMEM_BYTES 24576

typedef unsigned short ushortT;
typedef unsigned int uintT;
typedef unsigned char ucharT;
typedef __attribute__((ext_vector_type(8))) short short8;
typedef __attribute__((ext_vector_type(4))) float floatx4;
typedef __attribute__((ext_vector_type(2))) float floatx2;

__device__ __forceinline__ float bf2f(uintT u) {
    return __uint_as_float(u << 16);
}
__device__ __forceinline__ ushortT f2bf(float f) {
    uintT x = __float_as_uint(f);
    return (ushortT)((x + 0x7fffu + ((x >> 16) & 1u)) >> 16);
}
__device__ __forceinline__ void dec4p(uintT u, floatx2& lo, floatx2& hi) {
    lo = __builtin_amdgcn_cvt_pk_f32_fp8((int)u, false);
    hi = __builtin_amdgcn_cvt_pk_f32_fp8((int)u, true);
}
// pack hi16(a),hi16(b) -> (bf(b)<<16)|bf(a)  [exact for decoded fp8]
__device__ __forceinline__ uintT packbf(floatx2 v) {
    return __builtin_amdgcn_perm(__float_as_uint(v.y), __float_as_uint(v.x), 0x07060302u);
}

struct MP {
    const int* rowp; const int* colp; const int* batch;
    const float* X;
    const float *W1, *B1, *W2, *B2, *W3, *B3, *FW1, *FB1, *FW2, *FB2;
    ucharT *Z8, *Hb8, *Xb8;
    ushortT* Whi;
    float* invs; int* degi;
    uintT *indptr, *epack, *seg;
    int* bfill;
    float* sums; float* cnts;
    float* out;
    int N, E, G, NB, nbBin, nbAgg, nbG, total4, nbX16;
};

// ---- P0: bin tasks + W-prep tasks + X->fp8 tasks (+ zero sums) ------------
__device__ __forceinline__ void ph_prep(const MP& p, unsigned char* smem) {
    const int t = threadIdx.x;
    const int T0 = p.nbBin + 256 + p.nbX16;
    for (int task = blockIdx.x; task < T0; task += gridDim.x) {
        if (task < p.nbBin) {
            uintT* staged = (uintT*)smem;              // 8 KB
            int* target = (int*)(smem + 8192);         // 8 KB
            int* sval  = (int*)(smem + 16384);
            int* horig = (int*)(smem + 18432);
            int* pcnt  = (int*)(smem + 20480);
            int* gbase = (int*)(smem + 22528);
            const int e0 = task * EPW;
            const int cnt = min(EPW, p.E - e0);
            sval[t] = 0; sval[t + 256] = 0;
            __syncthreads();
            int er[8], ec[8];
#pragma unroll
            for (int i = 0; i < 8; ++i) {
                int le = i * 256 + t;
                if (le < cnt) {
                    er[i] = p.rowp[e0 + le];
                    ec[i] = p.colp[e0 + le];
                    atomicAdd(&sval[ec[i] >> BSH], 1);
                }
            }
            __syncthreads();
            horig[t] = sval[t]; horig[t + 256] = sval[t + 256];
            __syncthreads();
            for (int off = 1; off < 512; off <<= 1) {
                int a = (t >= off) ? sval[t - off] : 0;
                int b2 = sval[t + 256 - off];
                __syncthreads();
                sval[t] += a;
                sval[t + 256] += b2;
                __syncthreads();
            }
            for (int b = t; b < 512; b += 256) {
                int h = horig[b];
                pcnt[b] = sval[b] - h;
                gbase[b] = (h > 0 && b < p.NB) ? atomicAdd(&p.bfill[b], h) : 0;
            }
            __syncthreads();
#pragma unroll
            for (int i = 0; i < 8; ++i) {
                int le = i * 256 + t;
                if (le < cnt) {
                    int b = ec[i] >> BSH;
                    int j = atomicAdd(&pcnt[b], 1);
                    staged[j] = (uintT)er[i] | ((uintT)ec[i] << 16);
                    int lo = sval[b] - horig[b];
                    target[j] = b * SEG + gbase[b] + (j - lo);
                }
            }
            __syncthreads();
            for (int s = t; s < cnt; s += 256) p.seg[target[s]] = staged[s];
            __syncthreads();   // LDS reuse guard across tasks
        } else if (task < p.nbBin + 256) {
            int bb = task - p.nbBin;
            int idx = bb * 256 + t;   // 0..65535
            int m = idx >> 14;
            int r2 = idx & 16383;
            int n = r2 >> 7;
            int k = r2 & 127;
            const float* W = (m == 0) ? p.W1 : (m == 1) ? p.W2 : (m == 2) ? p.W3 : p.FW1;
            p.Whi[m * 16384 + n * CH + k] = f2bf(W[k * CH + n]);
            if (bb == 0 && t < 3 * p.G) p.sums[t] = 0.f;
        } else {
            int xb = task - p.nbBin - 256;
            int base = xb * 4096;
#pragma unroll
            for (int k = 0; k < 16; ++k) {
                int i = base + k * 256 + t;
                if (i < p.total4) {
                    float4 v = reinterpret_cast<const float4*>(p.X)[i];
                    int r0 = __builtin_amdgcn_cvt_pk_fp8_f32(v.x, v.y, 0, false);
                    int r1 = __builtin_amdgcn_cvt_pk_fp8_f32(v.z, v.w, r0, true);
                    reinterpret_cast<int*>(p.Xb8)[i] = r1;
                }
            }
        }
    }
}

// ---- P1: per-bucket degree -> invs + degi ---------------------------------
__device__ __forceinline__ void ph_binvs(const MP& p, unsigned char* smem) {
    const int t = threadIdx.x;
    int* h = (int*)smem;
    for (int b = blockIdx.x; b < p.NB; b += gridDim.x) {
        if (t < 128) h[t] = 0;
        __syncthreads();
        int cnt = p.bfill[b];
        const uintT* sp = p.seg + (size_t)b * SEG;
        for (int s = t; s < cnt; s += 256) atomicAdd(&h[(sp[s] >> 16) & 127], 1);
        __syncthreads();
        int d = b * 128 + t;
        if (t < 128 && d < p.N) {
            p.invs[d] = rsqrtf((float)h[t] + 1.0f);
            p.degi[d] = h[t];
        }
        __syncthreads();   // LDS reuse guard
    }
}

// ---- P2: per-bucket CSR scatter (padded x8, fixed segments) ---------------
__device__ __forceinline__ void ph_scatter(const MP& p, unsigned char* smem) {
    const int t = threadIdx.x;
    uintT* staged = (uintT*)smem;                 // 20480 B
    int* pinc = (int*)(smem + 20480);
    int* pc   = (int*)(smem + 20992);
    float* invL = (float*)(smem + 21504);
    int* ptotS = (int*)(smem + 22016);
    for (int b = blockIdx.x; b < p.NB; b += gridDim.x) {
        const int cnt = p.bfill[b];
        const uintT* sp = p.seg + (size_t)b * SEG;
        int praw = 0, hp = 0;
        if (t < 128) {
            int d = b * 128 + t;
            praw = (d < p.N) ? p.degi[d] : 0;
            invL[t] = (d < p.N) ? p.invs[d] : 0.f;
            hp = (praw + 7) & ~7;
            pinc[t] = hp;
        }
        __syncthreads();
        for (int off = 1; off < 128; off <<= 1) {
            int a = (t >= off && t < 128) ? pinc[t - off] : 0;
            __syncthreads();
            if (t < 128) pinc[t] += a;
            __syncthreads();
        }
        int excl = 0;
        if (t < 128) {
            excl = pinc[t] - hp;
            pc[t] = excl;
            int d = b * 128 + t;
            if (d < p.N) p.indptr[d] = (uintT)(b * SEGP + excl) | ((uintT)(hp >> 3) << 21);
            if (t == 127) ptotS[0] = pinc[127];
        }
        __syncthreads();
        for (int s = t; s < cnt; s += 256) {
            uintT rc = sp[s];
            int src = (int)(rc & 0xffffu);
            int d7 = (int)(rc >> 16) & 127;
            int j = atomicAdd(&pc[d7], 1);
            float nrm = p.invs[src] * invL[d7];
            staged[j] = (uintT)src | ((uintT)f2bf(nrm) << 16);
        }
        __syncthreads();
        if (t < 128) {
            for (int k = excl + praw; k < excl + hp; ++k) staged[k] = 0u;  // zero-weight pad
        }
        __syncthreads();
        {
            int tot4 = ptotS[0] >> 2;   // multiple of 8 records
            uint4* dstw = reinterpret_cast<uint4*>(p.epack + (size_t)b * SEGP);
            const uint4* srcw = reinterpret_cast<const uint4*>(staged);
            for (int s = t; s < tot4; s += 256) dstw[s] = srcw[s];
        }
        __syncthreads();   // LDS reuse guard
    }
}

// ---- agg: 8 nodes/wave x 8 lanes x 16ch; 2x uint4 = 8 edge recs -----------
__device__ __forceinline__ void ph_agg(const MP& p, const ucharT* H8, ucharT* Z8) {
    const int wave = threadIdx.x >> 6, lane = threadIdx.x & 63;
    const int ng = lane >> 3;
    const int l = lane & 7;
    const uint4* H4 = reinterpret_cast<const uint4*>(H8);
    const uint4* E4 = reinterpret_cast<const uint4*>(p.epack);

    for (int task = blockIdx.x; task < p.nbAgg; task += gridDim.x) {
        const int node = task * 32 + wave * 8 + ng;
        if (node < p.N) {
            uintT v = p.indptr[node];
            int q0 = (int)(v & 0x1FFFFFu) >> 2;
            int nb = (int)(v >> 21);

            floatx2 acc2[8];
            {
                float sn = p.invs[node];
                float sn2 = sn * sn;
                floatx2 s2 = {sn2, sn2};
                uint4 hrow = H4[(size_t)node * 8 + l];
                uintT wd[4] = {hrow.x, hrow.y, hrow.z, hrow.w};
#pragma unroll
                for (int w = 0; w < 4; ++w) {
                    floatx2 lo, hi;
                    dec4p(wd[w], lo, hi);
                    acc2[2 * w] = s2 * lo;
                    acc2[2 * w + 1] = s2 * hi;
                }
            }

            auto proc = [&](uint4 ea, uint4 eb) {
                uintT rec[8] = {ea.x, ea.y, ea.z, ea.w, eb.x, eb.y, eb.z, eb.w};
                uint4 g[8];
#pragma unroll
                for (int i = 0; i < 8; ++i)
                    g[i] = H4[(size_t)(int)(rec[i] & 0xffffu) * 8 + l];
#pragma unroll
                for (int i = 0; i < 8; ++i) {
                    float wv = bf2f(rec[i] >> 16);
                    floatx2 wv2 = {wv, wv};
                    uintT wd[4] = {g[i].x, g[i].y, g[i].z, g[i].w};
#pragma unroll
                    for (int w = 0; w < 4; ++w) {
                        floatx2 lo, hi;
                        dec4p(wd[w], lo, hi);
                        acc2[2 * w] += wv2 * lo;
                        acc2[2 * w + 1] += wv2 * hi;
                    }
                }
            };

            if (nb > 0) {
                uint4 ea = E4[q0], eb = E4[q0 + 1];
                for (int it = 1; it < nb; ++it) {
                    uint4 na = E4[q0 + 2 * it], nbv = E4[q0 + 2 * it + 1];
                    proc(ea, eb);
                    ea = na; eb = nbv;
                }
                proc(ea, eb);
            }

            uint4 o;
            {
                int r0 = __builtin_amdgcn_cvt_pk_fp8_f32(acc2[0].x, acc2[0].y, 0, false);
                r0 = __builtin_amdgcn_cvt_pk_fp8_f32(acc2[1].x, acc2[1].y, r0, true);
                int r1 = __builtin_amdgcn_cvt_pk_fp8_f32(acc2[2].x, acc2[2].y, 0, false);
                r1 = __builtin_amdgcn_cvt_pk_fp8_f32(acc2[3].x, acc2[3].y, r1, true);
                int r2 = __builtin_amdgcn_cvt_pk_fp8_f32(acc2[4].x, acc2[4].y, 0, false);
                r2 = __builtin_amdgcn_cvt_pk_fp8_f32(acc2[5].x, acc2[5].y, r2, true);
                int r3 = __builtin_amdgcn_cvt_pk_fp8_f32(acc2[6].x, acc2[6].y, 0, false);
                r3 = __builtin_amdgcn_cvt_pk_fp8_f32(acc2[7].x, acc2[7].y, r3, true);
                o.x = (uintT)r0; o.y = (uintT)r1; o.z = (uintT)r2; o.w = (uintT)r3;
            }
            reinterpret_cast<uint4*>(Z8)[(size_t)node * 8 + l] = o;
        }
    }
}

// ---- gemm: M=64 A-tile in LDS, W fragments direct from global (L2) --------
__device__ __forceinline__ void ph_gemm(const MP& p, const ucharT* In8,
                                        const ushortT* Whi, const float* Bias,
                                        ucharT* Out8, unsigned char* smem) {
    ushortT* As = (ushortT*)smem;   // 17408 B
    const int tid = threadIdx.x;
    const int wave = tid >> 6, lane = tid & 63;
    const int quad = lane >> 4, l15 = lane & 15;
    const int mBase = (wave >> 1) * 32, nBase = (wave & 1) * 64;
    const int r = tid >> 2, q = tid & 3;

    for (int task = blockIdx.x; task < p.nbG; task += gridDim.x) {
        const int row0 = task * 64;
        {
            int grow = row0 + r;
            uint4 a8 = {0, 0, 0, 0}, b8 = {0, 0, 0, 0};
            if (grow < p.N) {
                const uint4* s = reinterpret_cast<const uint4*>(In8 + (size_t)grow * CH + q * 32);
                a8 = s[0]; b8 = s[1];
            }
            uintT wds[8] = {a8.x, a8.y, a8.z, a8.w, b8.x, b8.y, b8.z, b8.w};
#pragma unroll
            for (int w = 0; w < 4; ++w) {
                floatx2 lo0, hi0, lo1, hi1;
                dec4p(wds[2 * w], lo0, hi0);
                dec4p(wds[2 * w + 1], lo1, hi1);
                uint4 o;
                o.x = packbf(lo0); o.y = packbf(hi0);
                o.z = packbf(lo1); o.w = packbf(hi1);
                *reinterpret_cast<uint4*>(&As[r * SAF + q * 32 + w * 8]) = o;
            }
        }
        __syncthreads();

        floatx4 acc[2][4];
        const floatx4 zero4 = {0.f, 0.f, 0.f, 0.f};
#pragma unroll
        for (int i = 0; i < 2; i++)
#pragma unroll
            for (int j = 0; j < 4; j++) acc[i][j] = zero4;

#pragma unroll
        for (int ks = 0; ks < 4; ++ks) {
            short8 af[2], wf[4];
#pragma unroll
            for (int mt = 0; mt < 2; ++mt)
                af[mt] = *reinterpret_cast<const short8*>(&As[(mBase + mt * 16 + l15) * SAF + ks * 32 + quad * 8]);
#pragma unroll
            for (int nt = 0; nt < 4; ++nt)
                wf[nt] = *reinterpret_cast<const short8*>(Whi + (size_t)(nBase + nt * 16 + l15) * CH + ks * 32 + quad * 8);
#pragma unroll
            for (int mt = 0; mt < 2; ++mt)
#pragma unroll
                for (int nt = 0; nt < 4; ++nt)
                    acc[mt][nt] = __builtin_amdgcn_mfma_f32_16x16x32_bf16(af[mt], wf[nt], acc[mt][nt], 0, 0, 0);
        }
        __syncthreads();   // all LDS reads done; reuse As as epilogue buffer

        float bb[4];
#pragma unroll
        for (int nt = 0; nt < 4; ++nt) bb[nt] = Bias[nBase + nt * 16 + l15];

        ucharT* Cs8 = reinterpret_cast<ucharT*>(As);
#pragma unroll
        for (int mt = 0; mt < 2; ++mt)
#pragma unroll
            for (int nt = 0; nt < 4; ++nt)
#pragma unroll
                for (int r4 = 0; r4 < 4; ++r4) {
                    int lrow = mBase + mt * 16 + quad * 4 + r4;
                    float v = fmaxf(acc[mt][nt][r4] + bb[nt], 0.f);
                    int f8 = __builtin_amdgcn_cvt_pk_fp8_f32(v, 0.f, 0, false);
                    Cs8[lrow * SC8 + nBase + nt * 16 + l15] = (ucharT)(f8 & 0xff);
                }
        __syncthreads();
        {
            int grow = row0 + r;
            if (grow < p.N) {
                const uint4* s4 = reinterpret_cast<const uint4*>(&Cs8[r * SC8 + q * 32]);
                uint4* dst = reinterpret_cast<uint4*>(Out8 + (size_t)grow * CH + q * 32);
                dst[0] = s4[0];
                dst[1] = s4[1];
            }
        }
        __syncthreads();   // LDS reuse guard
    }
}

// ---- tail: GEMM(W3)->relu->GEMM(FW1)->FC2->pool (M=64) --------------------
__device__ __forceinline__ void ph_tail(const MP& p, unsigned char* smem) {
    ushortT* Hf = (ushortT*)smem;                 // 17408 B
    float* rp0 = (float*)(smem + 17408);
    float* rp1 = (float*)(smem + 17920);
    float* ls  = (float*)(smem + 18432);          // 192 floats
    const ushortT* W3hi = p.Whi + 2 * 16384;
    const ushortT* F1hi = p.Whi + 3 * 16384;

    const int tid = threadIdx.x;
    const int wave = tid >> 6, lane = tid & 63;
    const int quad = lane >> 4, l15 = lane & 15;
    const int mBase = (wave >> 1) * 32, nBase = (wave & 1) * 64;
    const int r = tid >> 2, q = tid & 3;

    for (int task = blockIdx.x; task < p.nbG; task += gridDim.x) {
        const int row0 = task * 64;
        {
            int grow = row0 + r;
            uint4 a8 = {0, 0, 0, 0}, b8 = {0, 0, 0, 0};
            if (grow < p.N) {
                const uint4* s = reinterpret_cast<const uint4*>(p.Z8 + (size_t)grow * CH + q * 32);
                a8 = s[0]; b8 = s[1];
            }
            uintT wds[8] = {a8.x, a8.y, a8.z, a8.w, b8.x, b8.y, b8.z, b8.w};
#pragma unroll
            for (int w = 0; w < 4; ++w) {
                floatx2 lo0, hi0, lo1, hi1;
                dec4p(wds[2 * w], lo0, hi0);
                dec4p(wds[2 * w + 1], lo1, hi1);
                uint4 o;
                o.x = packbf(lo0); o.y = packbf(hi0);
                o.z = packbf(lo1); o.w = packbf(hi1);
                *reinterpret_cast<uint4*>(&Hf[r * SAF + q * 32 + w * 8]) = o;
            }
        }
        __syncthreads();

        floatx4 acc[2][4];
        const floatx4 zero4 = {0.f, 0.f, 0.f, 0.f};
#pragma unroll
        for (int i = 0; i < 2; i++)
#pragma unroll
            for (int j = 0; j < 4; j++) acc[i][j] = zero4;

        // GEMM 1: Z @ W3 (W3 fragments from global)
#pragma unroll
        for (int ks = 0; ks < 4; ++ks) {
            short8 af[2], wf[4];
#pragma unroll
            for (int mt = 0; mt < 2; ++mt)
                af[mt] = *reinterpret_cast<const short8*>(&Hf[(mBase + mt * 16 + l15) * SAF + ks * 32 + quad * 8]);
#pragma unroll
            for (int nt = 0; nt < 4; ++nt)
                wf[nt] = *reinterpret_cast<const short8*>(W3hi + (size_t)(nBase + nt * 16 + l15) * CH + ks * 32 + quad * 8);
#pragma unroll
            for (int mt = 0; mt < 2; ++mt)
#pragma unroll
                for (int nt = 0; nt < 4; ++nt)
                    acc[mt][nt] = __builtin_amdgcn_mfma_f32_16x16x32_bf16(af[mt], wf[nt], acc[mt][nt], 0, 0, 0);
        }
        __syncthreads();   // all GEMM1 LDS reads done

        // epilogue 1: H3 = relu(acc + b3) -> Hf
        {
            float bb[4];
#pragma unroll
            for (int nt = 0; nt < 4; ++nt) bb[nt] = p.B3[nBase + nt * 16 + l15];
#pragma unroll
            for (int mt = 0; mt < 2; ++mt)
#pragma unroll
                for (int nt = 0; nt < 4; ++nt)
#pragma unroll
                    for (int r4 = 0; r4 < 4; ++r4) {
                        int lrow = mBase + mt * 16 + quad * 4 + r4;
                        float v = fmaxf(acc[mt][nt][r4] + bb[nt], 0.f);
                        Hf[lrow * SAF + nBase + nt * 16 + l15] = f2bf(v);
                    }
        }
        __syncthreads();

        // GEMM 2: H3 @ FW1 (FW1 fragments from global)
#pragma unroll
        for (int i = 0; i < 2; i++)
#pragma unroll
            for (int j = 0; j < 4; j++) acc[i][j] = zero4;
#pragma unroll
        for (int ks = 0; ks < 4; ++ks) {
            short8 af[2], wf[4];
#pragma unroll
            for (int mt = 0; mt < 2; ++mt)
                af[mt] = *reinterpret_cast<const short8*>(&Hf[(mBase + mt * 16 + l15) * SAF + ks * 32 + quad * 8]);
#pragma unroll
            for (int nt = 0; nt < 4; ++nt)
                wf[nt] = *reinterpret_cast<const short8*>(F1hi + (size_t)(nBase + nt * 16 + l15) * CH + ks * 32 + quad * 8);
#pragma unroll
            for (int mt = 0; mt < 2; ++mt)
#pragma unroll
                for (int nt = 0; nt < 4; ++nt)
                    acc[mt][nt] = __builtin_amdgcn_mfma_f32_16x16x32_bf16(af[mt], wf[nt], acc[mt][nt], 0, 0, 0);
        }

        // FC2: per-row dot with fcW2, reduce over l15
        {
            float bb[4];
#pragma unroll
            for (int nt = 0; nt < 4; ++nt) bb[nt] = p.FB1[nBase + nt * 16 + l15];
            float w20[4], w21[4];
#pragma unroll
            for (int nt = 0; nt < 4; ++nt) {
                float2 wv = *reinterpret_cast<const float2*>(p.FW2 + 2 * (nBase + nt * 16 + l15));
                w20[nt] = wv.x;
                w21[nt] = wv.y;
            }
#pragma unroll
            for (int mt = 0; mt < 2; ++mt)
#pragma unroll
                for (int r4 = 0; r4 < 4; ++r4) {
                    float d0 = 0.f, d1 = 0.f;
#pragma unroll
                    for (int nt = 0; nt < 4; ++nt) {
                        float v = fmaxf(acc[mt][nt][r4] + bb[nt], 0.f);
                        d0 += v * w20[nt];
                        d1 += v * w21[nt];
                    }
#pragma unroll
                    for (int m = 8; m >= 1; m >>= 1) {
                        d0 += __shfl_xor(d0, m, 64);
                        d1 += __shfl_xor(d1, m, 64);
                    }
                    if (l15 == 0) {
                        int lrow = mBase + mt * 16 + quad * 4 + r4;
                        rp0[lrow * 2 + (wave & 1)] = d0;
                        rp1[lrow * 2 + (wave & 1)] = d1;
                    }
                }
        }
        if (tid < 192) ls[tid] = 0.f;
        __syncthreads();

        if (tid < 64) {
            int node = row0 + tid;
            if (node < p.N) {
                float d0 = rp0[tid * 2] + rp0[tid * 2 + 1] + p.FB2[0];
                float d1 = rp1[tid * 2] + rp1[tid * 2 + 1] + p.FB2[1];
                int g = p.batch[node];
                atomicAdd(&ls[g], d0);
                atomicAdd(&ls[64 + g], d1);
                atomicAdd(&ls[128 + g], 1.0f);
            }
        }
        __syncthreads();
        if (tid < 64) {
            float c = ls[128 + tid];
            if (c != 0.f) {
                atomicAdd(&p.sums[2 * tid], ls[tid]);
                atomicAdd(&p.sums[2 * tid + 1], ls[64 + tid]);
                atomicAdd(&p.cnts[tid], c);
            }
        }
        __syncthreads();   // LDS reuse guard
    }
}

__device__ __forceinline__ void ph_softmax(const MP& p) {
    const int t = threadIdx.x;
    if (blockIdx.x == 0 && t < p.G) {
        float c = fmaxf(atomicAdd(&p.cnts[t], 0.f), 1.0f);
        float p0 = atomicAdd(&p.sums[2 * t], 0.f) / c;
        float p1 = atomicAdd(&p.sums[2 * t + 1], 0.f) / c;
        float m = fmaxf(p0, p1);
        float e0 = expf(p0 - m), e1 = expf(p1 - m);
        float inv = 1.f / (e0 + e1);
        p.out[2 * t] = e0 * inv;
        p.out[2 * t + 1] = e1 * inv;
    }
}

// ---- cooperative mega-kernel ----------------------------------------------
__global__ __launch_bounds__(256) void k_mega(MP p) {
    __shared__ __align__(16) unsigned char smem[SMEM_BYTES];
    cg::grid_group grid = cg::this_grid();
    ph_prep(p, smem);                         grid.sync();
    ph_binvs(p, smem);                        grid.sync();
    ph_scatter(p, smem);                      grid.sync();
    ph_agg(p, p.Xb8, p.Z8);                   grid.sync();
    ph_gemm(p, p.Z8, p.Whi, p.B1, p.Hb8, smem);              grid.sync();
    ph_agg(p, p.Hb8, p.Z8);                   grid.sync();
    ph_gemm(p, p.Z8, p.Whi + 16384, p.B2, p.Hb8, smem);      grid.sync();
    ph_agg(p, p.Hb8, p.Z8);                   grid.sync();
    ph_tail(p, smem);                         grid.sync();
    ph_softmax(p);
}

// ---- fallback wrappers (multi-dispatch path) ------------------------------
__global__ __launch_bounds__(256) void k_prep(MP p) {
    __shared__ __align__(16) unsigned char smem[SMEM_BYTES];
    ph_prep(p, smem);
}
__global__ __launch_bounds__(256) void k_binvsW(MP p) {
    __shared__ __align__(16) unsigned char smem[SMEM_BYTES];
    ph_binvs(p, smem);
}
__global__ __launch_bounds__(256) void k_scatterW(MP p) {
    __shared__ __align__(16) unsigned char smem[SMEM_BYTES];
    ph_scatter(p, smem);
}
__global__ __launch_bounds__(256) void k_agg1(MP p) { ph_agg(p, p.Xb8, p.Z8); }
__global__ __launch_bounds__(256) void k_agg2(MP p) { ph_agg(p, p.Hb8, p.Z8); }
__global__ __launch_bounds__(256) void k_gemm1(MP p) {
    __shared__ __align__(16) unsigned char smem[SMEM_BYTES];
    ph_gemm(p, p.Z8, p.Whi, p.B1, p.Hb8, smem);
}
__global__ __launch_bounds__(256) void k_gemm2(MP p) {
    __shared__ __align__(16) unsigned char smem[SMEM_BYTES];
    ph_gemm(p, p.Z8, p.Whi + 16384, p.B2, p.Hb8, smem);
}
__global__ __launch_bounds__(256) void k_tailW(MP p) {
    __shared__ __align__(16) unsigned char smem[SMEM_BYTES];
    ph_tail(p, smem);
}
__global__ void k_softW(MP p) { ph_softmax(p); }

// ---------------------------------------------------------------------------
extern "C" void kernel_launch(void* const* d_in, const int* in_sizes, int n_in,
                              void* d_out, int out_size, void* d_ws, size_t ws_size,
                              hipStream_t stream) {
    MP P;
    P.X   = (const float*)d_in[0];
    const int* EI = (const int*)d_in[1];
    P.batch = (const int*)d_in[2];
    P.W1 = (const float*)d_in[3];  P.B1 = (const float*)d_in[4];
    P.W2 = (const float*)d_in[5];  P.B2 = (const float*)d_in[6];
    P.W3 = (const float*)d_in[7];  P.B3 = (const float*)d_in[8];
    P.FW1 = (const float*)d_in[9]; P.FB1 = (const float*)d_in[10];
    P.FW2 = (const float*)d_in[11]; P.FB2 = (const float*)d_in[12];

    P.N = in_sizes[0] / CH;
    P.E = in_sizes[1] / 2;
    P.G = out_size / 2;
    P.rowp = EI;
    P.colp = EI + P.E;
    P.NB = (P.N + 127) >> BSH;

    char* w = (char*)d_ws;
    auto alloc = [&](size_t bytes) -> char* {
        char* pp = w;
        w += (bytes + 255) & ~(size_t)255;
        return pp;
    };
    P.Z8   = (ucharT*)alloc((size_t)P.N * CH);
    P.Hb8  = (ucharT*)alloc((size_t)P.N * CH);
    P.Xb8  = (ucharT*)alloc((size_t)P.N * CH);
    P.Whi  = (ushortT*)alloc((size_t)4 * 16384 * 2);
    P.invs = (float*)alloc((size_t)P.N * 4);
    P.degi = (int*)alloc((size_t)P.N * 4);
    P.indptr = (uintT*)alloc((size_t)P.N * 4);
    P.epack  = (uintT*)alloc((size_t)P.NB * SEGP * 4);
    P.seg    = (uintT*)alloc((size_t)P.NB * SEG * 4);
    P.bfill  = (int*)alloc((size_t)P.NB * 4);
    P.sums   = (float*)alloc((size_t)P.G * 3 * 4);
    P.cnts   = P.sums + 2 * P.G;
    P.out    = (float*)d_out;

    P.nbBin  = (P.E + EPW - 1) / EPW;
    P.nbAgg  = (P.N + 31) / 32;
    P.nbG    = (P.N + 63) / 64;
    P.total4 = P.N * CH / 4;
    P.nbX16  = (P.total4 + 4095) / 4096;

    static int s_grid = -2;
    if (s_grid == -2) {
        int cus = 0, maxb = 0;
        if (hipDeviceGetAttribute(&cus, hipDeviceAttributeMultiprocessorCount, 0) != hipSuccess || cus <= 0)
            cus = 256;
        if (hipOccupancyMaxActiveBlocksPerMultiprocessor(&maxb, k_mega, 256, 0) != hipSuccess)
            maxb = 0;
        if (maxb > 0) {
            long g = (long)maxb * cus;
            s_grid = (g > 2048) ? 2048 : (int)g;
        } else {
            s_grid = -1;   // fallback multi-dispatch
        }
    }

    (void)hipMemsetAsync(P.bfill, 0, (size_t)P.NB * 4, stream);

    if (s_grid > 0) {
        MP Pl = P;
        void* args[] = { (void*)&Pl };
        (void)hipLaunchCooperativeKernel((const void*)k_mega, dim3(s_grid), dim3(256),
                                         args, 0, stream);
    } else {
        const int T0 = P.nbBin + 256 + P.nbX16;
        k_prep<<<T0, 256, 0, stream>>>(P);
        k_binvsW<<<P.NB, 256, 0, stream>>>(P);
        k_scatterW<<<P.NB, 256, 0, stream>>>(P);
        k_agg1<<<P.nbAgg, 256, 0, stream>>>(P);
        k_gemm1<<<P.nbG, 256, 0, stream>>>(P);
        k_agg2<<<P.nbAgg, 256, 0, stream>>>(P);
        k_gemm2<<<P.nbG, 256, 0, stream>>>(P);
        k_agg2<<<P.nbAgg, 256, 0, stream>>>(P);
        k_tailW<<<P.nbG, 256, 0, stream>>>(P);
        k_softW<<<1, 64, 0, stream>>>(P);
    }
}

// Round 9
// 206.057 us; speedup vs baseline: 2.6703x; 2.6703x over previous
//
#include <hip/hip_runtime.h>

// ---------------------------------------------------------------------------
// colorableGNN: 3x GCN(128->128) + FC(128->128) + FC(128->2) + mean-pool + softmax
// R23 = R22 with compile fix: __builtin_nontemporal_load requires a clang
// ext_vector pointer, not HIP_vector_type. (floatx4 ext_vector + swizzles.)
//  R20/R21 mega-kernel experiment: whole-pipeline counters showed intrinsic
//  work ~30-60us (FETCH+WRITE 176MB ~ 28us; VALU ~26us; MFMA ~3us) but
//  grid.sync() cost ~350us -> cooperative path abandoned; multi-dispatch
//  at ~204us is latency-bound with no single hot spot.
//  - Lever: X->fp8 conversion reads 25.6MB ONCE; nontemporal loads so they
//    don't evict L2/L3 data that layer-1 agg gathers.
//  - R17 structure: EPW 2048, weighted 4B edge records (src|bf16nrm), x8
//    zero-weight-padded epack (2x uint4 / 8-edge batch), full-K single-stage
//    GEMM LDS (M=128), fused softmax via tdone counter.
// NOTE: gather kernels need occupancy; never fuse agg into GEMM (R7: 104us).
// NOTE: no VGPR caps on k_agg (R19: spills); no global deg atomics (R16).
// ---------------------------------------------------------------------------

#define CH 128
#define BSH 7              // 128 dst nodes per bucket
#define SEG 4096           // raw segment capacity (records) per bucket
#define SEGP 5120          // padded epack segment (4B records) per bucket
#define EPW 2048           // edges per phase-1 workgroup
#define SAF 136            // LDS stride full-K tiles (shorts; 272B = 17*16B)
#define SC8 144            // fp8 epilogue stride (bytes)

typedef unsigned short ushortT;
typedef unsigned int uintT;
typedef unsigned char ucharT;
typedef __attribute__((ext_vector_type(8))) short short8;
typedef __attribute__((ext_vector_type(4))) float floatx4;
typedef __attribute__((ext_vector_type(2))) float floatx2;

__device__ __forceinline__ float bf2f(uintT u) {
    return __uint_as_float(u << 16);
}
__device__ __forceinline__ ushortT f2bf(float f) {
    uintT x = __float_as_uint(f);
    return (ushortT)((x + 0x7fffu + ((x >> 16) & 1u)) >> 16);
}
__device__ __forceinline__ void dec4(uintT u, float* o) {
    floatx2 lo = __builtin_amdgcn_cvt_pk_f32_fp8((int)u, false);
    floatx2 hi = __builtin_amdgcn_cvt_pk_f32_fp8((int)u, true);
    o[0] = lo.x; o[1] = lo.y; o[2] = hi.x; o[3] = hi.y;
}
__device__ __forceinline__ void dec16(uint4 v, float* o) {
    dec4(v.x, o); dec4(v.y, o + 4); dec4(v.z, o + 8); dec4(v.w, o + 12);
}

// ---- phase 1: bin edges into dst-buckets; records packed src|(dst<<16) ----
// extra blocks: [NBB, NBB+256) weight prep (+block0 zeroes sums/tdone);
//               [NBB+256, ...) X -> fp8 (unscaled, overlapped, NT loads)
__global__ __launch_bounds__(256) void k_bin(const int* __restrict__ row,
                                             const int* __restrict__ col,
                                             int* __restrict__ bfill,
                                             uintT* __restrict__ seg,
                                             const float* __restrict__ X,
                                             ucharT* __restrict__ Xb,
                                             const float* __restrict__ w0,
                                             const float* __restrict__ w1,
                                             const float* __restrict__ w2,
                                             const float* __restrict__ w3,
                                             ushortT* __restrict__ Whi,
                                             float* __restrict__ sums,
                                             int* __restrict__ tdone,
                                             int E, int NBB, int NB, int G,
                                             int total4) {
    __shared__ uintT staged[EPW];   // 8 KB
    __shared__ int target[EPW];     // 8 KB
    __shared__ int sval[512];
    __shared__ int horig[512];
    __shared__ int pcnt[512];
    __shared__ int gbase[512];
    const int t = threadIdx.x;

    if ((int)blockIdx.x >= NBB) {
        int bb = (int)blockIdx.x - NBB;
        if (bb < 256) {
            // weight prep: transpose + bf16
            int idx = bb * 256 + t;   // 0..65535
            int m = idx >> 14;
            int r2 = idx & 16383;
            int n = r2 >> 7;
            int k = r2 & 127;
            const float* W = (m == 0) ? w0 : (m == 1) ? w1 : (m == 2) ? w2 : w3;
            Whi[m * 16384 + n * CH + k] = f2bf(W[k * CH + n]);
            if (bb == 0) {
                if (t < 3 * G) sums[t] = 0.f;
                if (t == 0) tdone[0] = 0;
            }
        } else {
            // X -> fp8 (unscaled); nontemporal reads: X is 25.6MB, read ONCE,
            // and must not evict L2/L3 lines that layer-1 agg will gather.
            int i = (bb - 256) * 256 + t;
            if (i < total4) {
                const floatx4* xp = reinterpret_cast<const floatx4*>(X) + i;
                floatx4 v = __builtin_nontemporal_load(xp);
                int r0 = __builtin_amdgcn_cvt_pk_fp8_f32(v.x, v.y, 0, false);
                int r1 = __builtin_amdgcn_cvt_pk_fp8_f32(v.z, v.w, r0, true);
                reinterpret_cast<int*>(Xb)[i] = r1;
            }
        }
        return;
    }

    const int e0 = blockIdx.x * EPW;
    const int cnt = min(EPW, E - e0);

    sval[t] = 0; sval[t + 256] = 0;
    __syncthreads();

    int er[8], ec[8];
#pragma unroll
    for (int i = 0; i < 8; ++i) {
        int le = i * 256 + t;
        if (le < cnt) {
            er[i] = row[e0 + le];
            ec[i] = col[e0 + le];
            atomicAdd(&sval[ec[i] >> BSH], 1);
        }
    }
    __syncthreads();
    horig[t] = sval[t]; horig[t + 256] = sval[t + 256];
    __syncthreads();
    for (int off = 1; off < 512; off <<= 1) {
        int a = (t >= off) ? sval[t - off] : 0;
        int b2 = sval[t + 256 - off];
        __syncthreads();
        sval[t] += a;
        sval[t + 256] += b2;
        __syncthreads();
    }
    for (int b = t; b < 512; b += 256) {
        int h = horig[b];
        pcnt[b] = sval[b] - h;
        gbase[b] = (h > 0 && b < NB) ? atomicAdd(&bfill[b], h) : 0;
    }
    __syncthreads();
#pragma unroll
    for (int i = 0; i < 8; ++i) {
        int le = i * 256 + t;
        if (le < cnt) {
            int b = ec[i] >> BSH;
            int j = atomicAdd(&pcnt[b], 1);
            staged[j] = (uintT)er[i] | ((uintT)ec[i] << 16);
            int lo = sval[b] - horig[b];
            target[j] = b * SEG + gbase[b] + (j - lo);
        }
    }
    __syncthreads();
    for (int s = t; s < cnt; s += 256) seg[target[s]] = staged[s];
}

// ---- per-bucket degree -> invs (grid = NB) --------------------------------
__global__ __launch_bounds__(512) void k_binvs(const int* __restrict__ bfill,
                                               const uintT* __restrict__ seg,
                                               float* __restrict__ invs,
                                               int NB, int N) {
    const int b = blockIdx.x;
    const int t = threadIdx.x;
    __shared__ int h[128];
    if (t < 128) h[t] = 0;
    __syncthreads();
    int cnt = bfill[b];
    const uintT* sp = seg + (size_t)b * SEG;
    for (int s = t; s < cnt; s += 512) atomicAdd(&h[(sp[s] >> 16) & 127], 1);
    __syncthreads();
    int d = b * 128 + t;
    if (t < 128 && d < N) invs[d] = rsqrtf((float)h[t] + 1.0f);
}

// ---- per-bucket CSR scatter: padded x8 4B records, fixed segments ---------
__global__ __launch_bounds__(256) void k_scatter(const int* __restrict__ bfill,
                                                 const uintT* __restrict__ seg,
                                                 const float* __restrict__ invs,
                                                 uintT* __restrict__ indptr,
                                                 uintT* __restrict__ epack,
                                                 int N, int NB) {
    __shared__ __align__(16) uintT staged[SEGP];   // 20 KB
    __shared__ int h[128];
    __shared__ int pinc[128];
    __shared__ int pc[128];
    __shared__ float invL[128];
    __shared__ int ptotS;
    const int t = threadIdx.x;
    const int b = blockIdx.x;
    const int cnt = bfill[b];
    const uintT* sp = seg + (size_t)b * SEG;

    if (t < 128) {
        h[t] = 0;
        int d = b * 128 + t;
        invL[t] = (d < N) ? invs[d] : 0.f;
    }
    __syncthreads();
    for (int s = t; s < cnt; s += 256) atomicAdd(&h[(sp[s] >> 16) & 127], 1);
    __syncthreads();
    int praw = 0, hp = 0;
    if (t < 128) {
        praw = h[t];
        hp = (praw + 7) & ~7;
        pinc[t] = hp;
    }
    __syncthreads();
    for (int off = 1; off < 128; off <<= 1) {
        int a = (t >= off && t < 128) ? pinc[t - off] : 0;
        __syncthreads();
        if (t < 128) pinc[t] += a;
        __syncthreads();
    }
    int excl = 0;
    if (t < 128) {
        excl = pinc[t] - hp;
        pc[t] = excl;
        int d = b * 128 + t;
        if (d < N) indptr[d] = (uintT)(b * SEGP + excl) | ((uintT)(hp >> 3) << 21);
        if (t == 127) ptotS = pinc[127];
    }
    __syncthreads();
    for (int s = t; s < cnt; s += 256) {
        uintT rc = sp[s];
        int src = (int)(rc & 0xffffu);
        int d7 = (int)(rc >> 16) & 127;
        int j = atomicAdd(&pc[d7], 1);
        float nrm = invs[src] * invL[d7];
        staged[j] = (uintT)src | ((uintT)f2bf(nrm) << 16);
    }
    __syncthreads();
    if (t < 128) {
        for (int k = excl + praw; k < excl + hp; ++k) staged[k] = 0u;  // zero-weight pad
    }
    __syncthreads();
    {
        int tot4 = ptotS >> 2;   // ptot is a multiple of 8
        uint4* dstw = reinterpret_cast<uint4*>(epack + (size_t)b * SEGP);
        const uint4* srcw = reinterpret_cast<const uint4*>(staged);
        for (int s = t; s < tot4; s += 256) dstw[s] = srcw[s];
    }
}

// ---- aggregation: 8 nodes/wave x 8 lanes x 16ch; 2x uint4 = 8 edge recs ---
// weighted records (src|bf16nrm); pads are (0,0) -> contribute exactly 0.
__global__ __launch_bounds__(256) void k_agg(const ucharT* __restrict__ H8,
                                             const uintT* __restrict__ epack,
                                             const uintT* __restrict__ indptr,
                                             const float* __restrict__ invs,
                                             ucharT* __restrict__ Z8, int N) {
    const int wave = threadIdx.x >> 6, lane = threadIdx.x & 63;
    const int ng = lane >> 3;        // node slot 0..7
    const int l = lane & 7;          // 16 channels each (uint4)
    const int node = blockIdx.x * 32 + wave * 8 + ng;
    if (node >= N) return;

    const uint4* H4 = reinterpret_cast<const uint4*>(H8);
    const uint4* E4 = reinterpret_cast<const uint4*>(epack);

    uintT v = indptr[node];
    int q0 = (int)(v & 0x1FFFFFu) >> 2;   // uint4 index (4 recs each), even
    int nb = (int)(v >> 21);              // number of 8-edge batches

    float acc[16];
    {
        float sn = invs[node];
        float sn2 = sn * sn;
        float d[16];
        dec16(H4[(size_t)node * 8 + l], d);
#pragma unroll
        for (int j = 0; j < 16; ++j) acc[j] = sn2 * d[j];
    }

    auto proc = [&](uint4 ea, uint4 eb) {
        uintT rec[8] = {ea.x, ea.y, ea.z, ea.w, eb.x, eb.y, eb.z, eb.w};
        uint4 g[8];
#pragma unroll
        for (int i = 0; i < 8; ++i)
            g[i] = H4[(size_t)(int)(rec[i] & 0xffffu) * 8 + l];
#pragma unroll
        for (int i = 0; i < 8; ++i) {
            float wv = bf2f(rec[i] >> 16);
            float d[16];
            dec16(g[i], d);
#pragma unroll
            for (int j = 0; j < 16; ++j) acc[j] += wv * d[j];
        }
    };

    if (nb > 0) {
        uint4 ea = E4[q0], eb = E4[q0 + 1];
        for (int it = 1; it < nb; ++it) {
            uint4 na = E4[q0 + 2 * it], nbv = E4[q0 + 2 * it + 1];
            proc(ea, eb);
            ea = na; eb = nbv;
        }
        proc(ea, eb);
    }

    uint4 o;
    {
        int r0 = __builtin_amdgcn_cvt_pk_fp8_f32(acc[0], acc[1], 0, false);
        r0 = __builtin_amdgcn_cvt_pk_fp8_f32(acc[2], acc[3], r0, true);
        int r1 = __builtin_amdgcn_cvt_pk_fp8_f32(acc[4], acc[5], 0, false);
        r1 = __builtin_amdgcn_cvt_pk_fp8_f32(acc[6], acc[7], r1, true);
        int r2 = __builtin_amdgcn_cvt_pk_fp8_f32(acc[8], acc[9], 0, false);
        r2 = __builtin_amdgcn_cvt_pk_fp8_f32(acc[10], acc[11], r2, true);
        int r3 = __builtin_amdgcn_cvt_pk_fp8_f32(acc[12], acc[13], 0, false);
        r3 = __builtin_amdgcn_cvt_pk_fp8_f32(acc[14], acc[15], r3, true);
        o.x = (uintT)r0; o.y = (uintT)r1; o.z = (uintT)r2; o.w = (uintT)r3;
    }
    reinterpret_cast<uint4*>(Z8)[(size_t)node * 8 + l] = o;
}

// ---- MFMA GEMM (GCN layers 1,2): fp8 in, fp8 out, full-K single stage -----
__global__ __launch_bounds__(256) void k_gemm(const ucharT* __restrict__ In8,
                                              const ushortT* __restrict__ Whi,
                                              const float* __restrict__ Bias,
                                              ucharT* __restrict__ Out8, int N) {
    __shared__ ushortT As[128 * SAF];   // 34816 B
    __shared__ ushortT Ws[128 * SAF];   // 34816 B

    const int tid = threadIdx.x;
    const int wave = tid >> 6, lane = tid & 63;
    const int quad = lane >> 4, l15 = lane & 15;
    const int mBase = (wave >> 1) * 64, nBase = (wave & 1) * 64;
    const int row0 = blockIdx.x * 128;
    const int r = tid >> 1, half = tid & 1;

    // stage A: full fp8 half-row (64B) -> bf16 LDS; stage W: bf16 copy
    {
        int grow = row0 + r;
        uint4 a8 = {0, 0, 0, 0}, b8 = {0, 0, 0, 0}, c8 = {0, 0, 0, 0}, d8v = {0, 0, 0, 0};
        if (grow < N) {
            const uint4* s = reinterpret_cast<const uint4*>(In8 + (size_t)grow * CH + half * 64);
            a8 = s[0]; b8 = s[1]; c8 = s[2]; d8v = s[3];
        }
        uintT wds[16] = {a8.x, a8.y, a8.z, a8.w, b8.x, b8.y, b8.z, b8.w,
                         c8.x, c8.y, c8.z, c8.w, d8v.x, d8v.y, d8v.z, d8v.w};
#pragma unroll
        for (int q = 0; q < 16; ++q) {
            float d[4];
            dec4(wds[q], d);
            uint2 o;
            o.x = (uintT)f2bf(d[0]) | ((uintT)f2bf(d[1]) << 16);
            o.y = (uintT)f2bf(d[2]) | ((uintT)f2bf(d[3]) << 16);
            *reinterpret_cast<uint2*>(&As[r * SAF + half * 64 + q * 4]) = o;
        }
        const uint4* sh = reinterpret_cast<const uint4*>(Whi + r * CH + half * 64);
#pragma unroll
        for (int q = 0; q < 8; ++q)
            *reinterpret_cast<uint4*>(&Ws[r * SAF + half * 64 + q * 8]) = sh[q];
    }
    __syncthreads();

    floatx4 acc[4][4];
    const floatx4 zero4 = {0.f, 0.f, 0.f, 0.f};
#pragma unroll
    for (int i = 0; i < 4; i++)
#pragma unroll
        for (int j = 0; j < 4; j++) acc[i][j] = zero4;

#pragma unroll
    for (int ks = 0; ks < 4; ++ks) {
        short8 af[4], wf[4];
#pragma unroll
        for (int mt = 0; mt < 4; ++mt)
            af[mt] = *reinterpret_cast<const short8*>(&As[(mBase + mt * 16 + l15) * SAF + ks * 32 + quad * 8]);
#pragma unroll
        for (int nt = 0; nt < 4; ++nt)
            wf[nt] = *reinterpret_cast<const short8*>(&Ws[(nBase + nt * 16 + l15) * SAF + ks * 32 + quad * 8]);
#pragma unroll
        for (int mt = 0; mt < 4; ++mt)
#pragma unroll
            for (int nt = 0; nt < 4; ++nt)
                acc[mt][nt] = __builtin_amdgcn_mfma_f32_16x16x32_bf16(af[mt], wf[nt], acc[mt][nt], 0, 0, 0);
    }
    __syncthreads();   // all LDS reads done; reuse As as epilogue buffer

    float bb[4];
#pragma unroll
    for (int nt = 0; nt < 4; ++nt) bb[nt] = Bias[nBase + nt * 16 + l15];

    ucharT* Cs8 = reinterpret_cast<ucharT*>(As);
#pragma unroll
    for (int mt = 0; mt < 4; ++mt)
#pragma unroll
        for (int nt = 0; nt < 4; ++nt)
#pragma unroll
            for (int r4 = 0; r4 < 4; ++r4) {
                int lrow = mBase + mt * 16 + quad * 4 + r4;
                float v = fmaxf(acc[mt][nt][r4] + bb[nt], 0.f);
                int f8 = __builtin_amdgcn_cvt_pk_fp8_f32(v, 0.f, 0, false);
                Cs8[lrow * SC8 + nBase + nt * 16 + l15] = (ucharT)(f8 & 0xff);
            }
    __syncthreads();
    {
        int grow = row0 + r;
        if (grow < N) {
            const uint4* s4 = reinterpret_cast<const uint4*>(&Cs8[r * SC8 + half * 64]);
            uint4* dst = reinterpret_cast<uint4*>(Out8 + (size_t)grow * CH + half * 64);
#pragma unroll
            for (int q = 0; q < 4; ++q) dst[q] = s4[q];
        }
    }
}

// ---- fused tail: GEMM(W3) -> relu -> GEMM(FW1) -> FC2 -> pool -> softmax --
__global__ __launch_bounds__(256) void k_tail(const ucharT* __restrict__ Z8,
                                              const ushortT* __restrict__ W3hi,
                                              const float* __restrict__ B3,
                                              const ushortT* __restrict__ F1hi,
                                              const float* __restrict__ FB1,
                                              const float* __restrict__ FW2,
                                              const float* __restrict__ FB2,
                                              const int* __restrict__ batch,
                                              float* __restrict__ sums,
                                              float* __restrict__ cnts,
                                              float* __restrict__ out,
                                              int* __restrict__ tdone,
                                              int N, int G) {
    __shared__ ushortT Hf[128 * SAF];   // 34816 B: A-tile (Z), then H3 tile
    __shared__ ushortT Ws[128 * SAF];   // 34816 B: W3, then FW1
    __shared__ float rp0[256];
    __shared__ float rp1[256];
    __shared__ float ls[192];
    __shared__ int lastFlag;

    const int tid = threadIdx.x;
    const int wave = tid >> 6, lane = tid & 63;
    const int quad = lane >> 4, l15 = lane & 15;
    const int mBase = (wave >> 1) * 64, nBase = (wave & 1) * 64;
    const int row0 = blockIdx.x * 128;
    const int r = tid >> 1, half = tid & 1;

    // stage full Z tile: fp8 -> bf16 into Hf; stage Ws = W3 full
    {
        int grow = row0 + r;
        uint4 a8 = {0, 0, 0, 0}, b8 = {0, 0, 0, 0}, c8 = {0, 0, 0, 0}, d8v = {0, 0, 0, 0};
        if (grow < N) {
            const uint4* s = reinterpret_cast<const uint4*>(Z8 + (size_t)grow * CH + half * 64);
            a8 = s[0]; b8 = s[1]; c8 = s[2]; d8v = s[3];
        }
        uintT wds[16] = {a8.x, a8.y, a8.z, a8.w, b8.x, b8.y, b8.z, b8.w,
                         c8.x, c8.y, c8.z, c8.w, d8v.x, d8v.y, d8v.z, d8v.w};
#pragma unroll
        for (int q = 0; q < 16; ++q) {
            float d[4];
            dec4(wds[q], d);
            uint2 o;
            o.x = (uintT)f2bf(d[0]) | ((uintT)f2bf(d[1]) << 16);
            o.y = (uintT)f2bf(d[2]) | ((uintT)f2bf(d[3]) << 16);
            *reinterpret_cast<uint2*>(&Hf[r * SAF + half * 64 + q * 4]) = o;
        }
        const uint4* sh = reinterpret_cast<const uint4*>(W3hi + r * CH + half * 64);
#pragma unroll
        for (int q = 0; q < 8; ++q)
            *reinterpret_cast<uint4*>(&Ws[r * SAF + half * 64 + q * 8]) = sh[q];
    }
    __syncthreads();

    floatx4 acc[4][4];
    const floatx4 zero4 = {0.f, 0.f, 0.f, 0.f};
#pragma unroll
    for (int i = 0; i < 4; i++)
#pragma unroll
        for (int j = 0; j < 4; j++) acc[i][j] = zero4;

    // GEMM 1: Z @ W3
#pragma unroll
    for (int ks = 0; ks < 4; ++ks) {
        short8 af[4], wf[4];
#pragma unroll
        for (int mt = 0; mt < 4; ++mt)
            af[mt] = *reinterpret_cast<const short8*>(&Hf[(mBase + mt * 16 + l15) * SAF + ks * 32 + quad * 8]);
#pragma unroll
        for (int nt = 0; nt < 4; ++nt)
            wf[nt] = *reinterpret_cast<const short8*>(&Ws[(nBase + nt * 16 + l15) * SAF + ks * 32 + quad * 8]);
#pragma unroll
        for (int mt = 0; mt < 4; ++mt)
#pragma unroll
            for (int nt = 0; nt < 4; ++nt)
                acc[mt][nt] = __builtin_amdgcn_mfma_f32_16x16x32_bf16(af[mt], wf[nt], acc[mt][nt], 0, 0, 0);
    }
    __syncthreads();   // all GEMM1 LDS reads done

    // epilogue 1: H3 = relu(acc + b3) -> Hf ; restage Ws = FW1
    {
        float bb[4];
#pragma unroll
        for (int nt = 0; nt < 4; ++nt) bb[nt] = B3[nBase + nt * 16 + l15];
#pragma unroll
        for (int mt = 0; mt < 4; ++mt)
#pragma unroll
            for (int nt = 0; nt < 4; ++nt)
#pragma unroll
                for (int r4 = 0; r4 < 4; ++r4) {
                    int lrow = mBase + mt * 16 + quad * 4 + r4;
                    float v = fmaxf(acc[mt][nt][r4] + bb[nt], 0.f);
                    Hf[lrow * SAF + nBase + nt * 16 + l15] = f2bf(v);
                }
        const uint4* sh = reinterpret_cast<const uint4*>(F1hi + r * CH + half * 64);
#pragma unroll
        for (int q = 0; q < 8; ++q)
            *reinterpret_cast<uint4*>(&Ws[r * SAF + half * 64 + q * 8]) = sh[q];
    }
    __syncthreads();

    // GEMM 2: H3 @ FW1
#pragma unroll
    for (int i = 0; i < 4; i++)
#pragma unroll
        for (int j = 0; j < 4; j++) acc[i][j] = zero4;
#pragma unroll
    for (int ks = 0; ks < 4; ++ks) {
        short8 af[4], wf[4];
#pragma unroll
        for (int mt = 0; mt < 4; ++mt)
            af[mt] = *reinterpret_cast<const short8*>(&Hf[(mBase + mt * 16 + l15) * SAF + ks * 32 + quad * 8]);
#pragma unroll
        for (int nt = 0; nt < 4; ++nt)
            wf[nt] = *reinterpret_cast<const short8*>(&Ws[(nBase + nt * 16 + l15) * SAF + ks * 32 + quad * 8]);
#pragma unroll
        for (int mt = 0; mt < 4; ++mt)
#pragma unroll
            for (int nt = 0; nt < 4; ++nt)
                acc[mt][nt] = __builtin_amdgcn_mfma_f32_16x16x32_bf16(af[mt], wf[nt], acc[mt][nt], 0, 0, 0);
    }

    // FC2: per-row dot with fcW2 over this lane's 4 columns, reduce over l15
    {
        float bb[4];
#pragma unroll
        for (int nt = 0; nt < 4; ++nt) bb[nt] = FB1[nBase + nt * 16 + l15];
        float w20[4], w21[4];
#pragma unroll
        for (int nt = 0; nt < 4; ++nt) {
            float2 wv = *reinterpret_cast<const float2*>(FW2 + 2 * (nBase + nt * 16 + l15));
            w20[nt] = wv.x;
            w21[nt] = wv.y;
        }
#pragma unroll
        for (int mt = 0; mt < 4; ++mt)
#pragma unroll
            for (int r4 = 0; r4 < 4; ++r4) {
                float d0 = 0.f, d1 = 0.f;
#pragma unroll
                for (int nt = 0; nt < 4; ++nt) {
                    float v = fmaxf(acc[mt][nt][r4] + bb[nt], 0.f);
                    d0 += v * w20[nt];
                    d1 += v * w21[nt];
                }
#pragma unroll
                for (int m = 8; m >= 1; m >>= 1) {
                    d0 += __shfl_xor(d0, m, 64);
                    d1 += __shfl_xor(d1, m, 64);
                }
                if (l15 == 0) {
                    int lrow = mBase + mt * 16 + quad * 4 + r4;
                    rp0[lrow * 2 + (wave & 1)] = d0;
                    rp1[lrow * 2 + (wave & 1)] = d1;
                }
            }
    }
    if (tid < 192) ls[tid] = 0.f;
    __syncthreads();

    if (tid < 128) {
        int node = row0 + tid;
        if (node < N) {
            float d0 = rp0[tid * 2] + rp0[tid * 2 + 1] + FB2[0];
            float d1 = rp1[tid * 2] + rp1[tid * 2 + 1] + FB2[1];
            int g = batch[node];
            atomicAdd(&ls[g], d0);
            atomicAdd(&ls[64 + g], d1);
            atomicAdd(&ls[128 + g], 1.0f);
        }
    }
    __syncthreads();
    if (tid < 64) {
        float c = ls[128 + tid];
        if (c != 0.f) {
            atomicAdd(&sums[2 * tid], ls[tid]);
            atomicAdd(&sums[2 * tid + 1], ls[64 + tid]);
            atomicAdd(&cnts[tid], c);
        }
    }
    __syncthreads();   // drains this block's global atomics

    // completion counter; last block computes softmax (coherent-point reads)
    if (tid == 0) {
        int old = atomicAdd(tdone, 1);
        lastFlag = (old == (int)gridDim.x - 1) ? 1 : 0;
    }
    __syncthreads();
    if (lastFlag && tid < G) {
        int g = tid;
        float c = fmaxf(atomicAdd(&cnts[g], 0.f), 1.0f);
        float p0 = atomicAdd(&sums[2 * g], 0.f) / c;
        float p1 = atomicAdd(&sums[2 * g + 1], 0.f) / c;
        float m = fmaxf(p0, p1);
        float e0 = expf(p0 - m), e1 = expf(p1 - m);
        float inv = 1.f / (e0 + e1);
        out[2 * g] = e0 * inv;
        out[2 * g + 1] = e1 * inv;
    }
}

// ---------------------------------------------------------------------------
extern "C" void kernel_launch(void* const* d_in, const int* in_sizes, int n_in,
                              void* d_out, int out_size, void* d_ws, size_t ws_size,
                              hipStream_t stream) {
    const float* X   = (const float*)d_in[0];
    const int* EI    = (const int*)d_in[1];
    const int* BATCH = (const int*)d_in[2];
    const float* W1  = (const float*)d_in[3];
    const float* B1  = (const float*)d_in[4];
    const float* W2  = (const float*)d_in[5];
    const float* B2  = (const float*)d_in[6];
    const float* W3  = (const float*)d_in[7];
    const float* B3  = (const float*)d_in[8];
    const float* FW1 = (const float*)d_in[9];
    const float* FB1 = (const float*)d_in[10];
    const float* FW2 = (const float*)d_in[11];
    const float* FB2 = (const float*)d_in[12];

    const int N = in_sizes[0] / CH;
    const int E = in_sizes[1] / 2;
    const int G = out_size / 2;
    const int* rowp = EI;
    const int* colp = EI + E;
    const int NB = (N + 127) >> BSH;

    char* w = (char*)d_ws;
    auto alloc = [&](size_t bytes) -> char* {
        char* p = w;
        w += (bytes + 255) & ~(size_t)255;
        return p;
    };
    ucharT*  Z8    = (ucharT*)alloc((size_t)N * CH);        // fp8 Z (agg out)
    ucharT*  Hb8   = (ucharT*)alloc((size_t)N * CH);        // fp8 H1/H2
    ucharT*  Xb8   = (ucharT*)alloc((size_t)N * CH);        // fp8 X
    ushortT* WhiA  = (ushortT*)alloc((size_t)4 * 16384 * 2);
    float* invs    = (float*)alloc((size_t)N * 4);
    uintT* indptr  = (uintT*)alloc((size_t)N * 4);
    uintT* epack   = (uintT*)alloc((size_t)NB * SEGP * 4);
    uintT* seg     = (uintT*)alloc((size_t)NB * SEG * 4);
    int*   bfill   = (int*)alloc((size_t)NB * 4);
    float* sums    = (float*)alloc((size_t)G * 3 * 4);      // sums | cnts
    float* cnts    = sums + 2 * G;
    int*   tdone   = (int*)alloc(256);

    const int nbAgg  = (N + 31) / 32;
    const int nbGemm = (N + 127) / 128;
    const int nbBin  = (E + EPW - 1) / EPW;
    const int total4 = N * CH / 4;
    const int nbXc   = (total4 + 255) / 256;

    (void)hipMemsetAsync(bfill, 0, (size_t)NB * 4, stream);
    k_bin<<<nbBin + 256 + nbXc, 256, 0, stream>>>(rowp, colp, bfill, seg,
                                                  X, Xb8, W1, W2, W3, FW1, WhiA,
                                                  sums, tdone, E, nbBin, NB, G, total4);
    k_binvs<<<NB, 512, 0, stream>>>(bfill, seg, invs, NB, N);
    k_scatter<<<NB, 256, 0, stream>>>(bfill, seg, invs, indptr, epack, N, NB);

    // layer 1
    k_agg<<<nbAgg, 256, 0, stream>>>(Xb8, epack, indptr, invs, Z8, N);
    k_gemm<<<nbGemm, 256, 0, stream>>>(Z8, WhiA, B1, Hb8, N);
    // layer 2
    k_agg<<<nbAgg, 256, 0, stream>>>(Hb8, epack, indptr, invs, Z8, N);
    k_gemm<<<nbGemm, 256, 0, stream>>>(Z8, WhiA + 16384, B2, Hb8, N);
    // layer 3 agg, then fused tail (GEMM W3 + FC1 + FC2 + pool + softmax)
    k_agg<<<nbAgg, 256, 0, stream>>>(Hb8, epack, indptr, invs, Z8, N);
    k_tail<<<nbGemm, 256, 0, stream>>>(Z8, WhiA + 2 * 16384, B3,
                                       WhiA + 3 * 16384, FB1, FW2, FB2,
                                       BATCH, sums, cnts, (float*)d_out, tdone, N, G);
}